// Round 11
// baseline (281.371 us; speedup 1.0000x reference)
//
#include <hip/hip_runtime.h>

// Problem constants (fixed shapes)
#define BB 8192      // batch
#define DZ 1024
#define DS 64
#define DH 4096
#define KEXT (DH + DS)   // 4160: K of GEMM2 = [H | s]

typedef float floatx4 __attribute__((ext_vector_type(4)));
typedef __bf16 bf16x8 __attribute__((ext_vector_type(8)));
typedef __attribute__((address_space(1))) void* as1_void_ptr;
typedef __attribute__((address_space(3))) void* as3_void_ptr;

// s_waitcnt immediates (gfx9: vmcnt[3:0] bits0-3 + [5:4] bits15:14,
// expcnt bits6:4, lgkmcnt bits11:8). lgkm=15,exp=7 "unconstrained" base = 3952.
#define WAIT_VM0   3952   // vmcnt(0)
#define WAIT_VM3   3955   // vmcnt(3)
#define WAIT_VM6   3958   // vmcnt(6)
#define WAIT_LGKM0 49279  // lgkmcnt(0), vm/exp unconstrained

__device__ __forceinline__ void async_copy16(const void* g, void* l) {
    __builtin_amdgcn_global_load_lds((as1_void_ptr)g, (as3_void_ptr)l, 16, 0, 0);
}

__device__ __forceinline__ bf16x8 cvt8(float4 a, float4 b) {
    bf16x8 o = { (__bf16)a.x, (__bf16)a.y, (__bf16)a.z, (__bf16)a.w,
                 (__bf16)b.x, (__bf16)b.y, (__bf16)b.z, (__bf16)b.w };
    return o;
}

// LDS swizzle (VERIFIED R1: conflicts 8.5M -> 0): panels [rows x 32] bf16;
// physical 16B chunk p of row r holds K-chunk p ^ ((r>>1)&3). Staging src:
// thread t loads global chunk (t&3)^((t>>3)&3); read chunk = (lane>>4)^((lane>>1)&3).
//
// SESSION LEDGER: R1 swizzle (real on gemm1); R3/R6/R8 restructures REGRESSED;
// prep BW-bound ~15us; ~75us/iter fixed harness overhead. gemm1 74.6us=921TF
// (3 blk/CU residency ceiling); gemm2 85-88us=810TF across 3 two-phase forms.
// R11: 8-phase counted-vmcnt on gemm2 -- the correct regime for T3+T4 (grid
// capped at 1 blk/CU so no residency alternative; K=65 tiles amortizes fill;
// R8 proved the macro race-free). gemm1/prep frozen as control.

// ---------------- prep: streaming f32->bf16 repack ----------------
__global__ __launch_bounds__(256) void prep_all(
    const float* __restrict__ z, const float* __restrict__ W1,
    const float* __restrict__ W2, const float* __restrict__ C,
    const float* __restrict__ s,
    __bf16* __restrict__ zb, __bf16* __restrict__ W1b,
    __bf16* __restrict__ B2b, __bf16* __restrict__ Hb)
{
    constexpr int NC_Z  = (BB * DZ) / 8;
    constexpr int NC_W1 = (DH * DZ) / 8;
    constexpr int NC_B2 = (DZ * KEXT) / 8;
    constexpr int NC_S  = (BB * DS) / 8;
    constexpr int NC_TOT = NC_Z + NC_W1 + NC_B2 + NC_S;
    const int stride = gridDim.x * blockDim.x;
    for (int c = blockIdx.x * blockDim.x + threadIdx.x; c < NC_TOT; c += stride) {
        const float4* src;
        __bf16* dst;
        if (c < NC_Z) {
            src = (const float4*)z + (size_t)c * 2;
            dst = zb + (size_t)c * 8;
        } else if (c < NC_Z + NC_W1) {
            int i = c - NC_Z;
            src = (const float4*)W1 + (size_t)i * 2;
            dst = W1b + (size_t)i * 8;
        } else if (c < NC_Z + NC_W1 + NC_B2) {
            int i = c - (NC_Z + NC_W1);
            int j = i / 520, p = i - j * 520;
            int h = p * 8;
            const float* sp = (h < DH) ? (W2 + (size_t)j * DH + h)
                                       : (C  + (size_t)j * DS + (h - DH));
            src = (const float4*)sp;
            dst = B2b + (size_t)j * KEXT + h;
        } else {
            int i = c - (NC_Z + NC_W1 + NC_B2);
            int r = i >> 3, k = (i & 7) * 8;
            src = (const float4*)(s + (size_t)r * DS + k);
            dst = Hb + (size_t)r * KEXT + DH + k;
        }
        float4 a = src[0], b = src[1];
        *(bf16x8*)dst = cvt8(a, b);
    }
}

// ---------------- GEMM1 (R4-FROZEN): Hb[:, :4096] = relu(zb @ W1b^T + h1) ----
// 256x128, 8 waves of 64x64, BK=64, single-buffer, 48KB, 3 blk/CU. 921 TF.
__global__ __launch_bounds__(512, 4) void gemm1_relu(
    const __bf16* __restrict__ Ag, const __bf16* __restrict__ Bg,
    const float* __restrict__ h1, __bf16* __restrict__ Hb)
{
    constexpr int ldA = DZ, ldB = DZ, KITER = DZ / 64;
    __shared__ __align__(16) __bf16 As[256 * 64];
    __shared__ __align__(16) __bf16 Bs[128 * 64];

    const int tid = threadIdx.x;
    const int wave = tid >> 6, lane = tid & 63;
    const int wm = wave >> 1, wn = wave & 1;
    const int row0 = blockIdx.x * 256;
    const int col0 = blockIdx.y * 128;

    const int csrc = ((tid & 3) ^ ((tid >> 3) & 3)) * 8;
    const __bf16* pA = Ag + (size_t)(row0 + (tid >> 2)) * ldA + csrc;
    const __bf16* pB = Bg + (size_t)(col0 + ((tid >> 2) & 127)) * ldB + csrc;
    __bf16* lA = As + wave * 512;
    __bf16* lB = Bs + wave * 512;

    const int cswz = ((lane >> 4) ^ ((lane >> 1) & 3)) * 8;
    const __bf16* Afrag = As + (wm * 64 + (lane & 15)) * 32 + cswz;
    const __bf16* Bfrag = Bs + (wn * 64 + (lane & 15)) * 32 + cswz;

    floatx4 acc[4][4];
#pragma unroll
    for (int i = 0; i < 4; ++i)
#pragma unroll
        for (int j = 0; j < 4; ++j) acc[i][j] = (floatx4)0.0f;

    for (int kt = 0; kt < KITER; ++kt) {
        const __bf16* ak = pA + kt * 64;
        const __bf16* bk = pB + kt * 64;
        async_copy16(ak,                           lA);
        async_copy16(ak + (size_t)128 * ldA,       lA + 4096);
        async_copy16(ak + 32,                      lA + 8192);
        async_copy16(ak + (size_t)128 * ldA + 32,  lA + 8192 + 4096);
        async_copy16(bk,                           lB);
        async_copy16(bk + 32,                      lB + 4096);
        __builtin_amdgcn_s_waitcnt(0);
        __syncthreads();

#pragma unroll
        for (int ks = 0; ks < 2; ++ks) {
            bf16x8 af[4], bfr[4];
#pragma unroll
            for (int i = 0; i < 4; ++i) af[i] = *(const bf16x8*)(Afrag + ks * 8192 + i * 16 * 32);
#pragma unroll
            for (int j = 0; j < 4; ++j) bfr[j] = *(const bf16x8*)(Bfrag + ks * 4096 + j * 16 * 32);
#pragma unroll
            for (int i = 0; i < 4; ++i)
#pragma unroll
                for (int j = 0; j < 4; ++j)
                    acc[i][j] = __builtin_amdgcn_mfma_f32_16x16x32_bf16(af[i], bfr[j], acc[i][j], 0, 0, 0);
        }
        __syncthreads();
    }

    const int r0 = row0 + wm * 64 + (lane >> 4) * 4;
    const int c0 = col0 + wn * 64 + (lane & 15);
#pragma unroll
    for (int i = 0; i < 4; ++i) {
#pragma unroll
        for (int j = 0; j < 4; ++j) {
            int c = c0 + j * 16;
            float bias = h1[c];
#pragma unroll
            for (int rg = 0; rg < 4; ++rg) {
                int r = r0 + i * 16 + rg;
                float v = acc[i][j][rg] + bias;
                v = v > 0.0f ? v : 0.0f;
                Hb[(size_t)r * KEXT + c] = (__bf16)v;
            }
        }
    }
}

// ---------------- GEMM2 (R11): 8-phase counted-vmcnt ----------------
// 256x128 tile, 8 waves (4M x 2N) of 64x64, BK=64, 96KB dbuf, grid 256
// = 1 blk/CU. Phase = (buf Q, ks-half KS, i-half IH):
//   ih0: 2 A-frag + 4 B-frag ds_reads; ih1: 2 A-frag (bfr reused).
//   One stage unit per phase; barrier; lgkm(0); setprio(1) 8 MFMA; [vm];
//   barrier. Stage units: sA0/sA1 = 2 gload_lds (16KB panel), sB0/sB1 = 1.
// Ring (iteration r, tiles t0=2r[buf0] t1=2r+1[buf1], t2=2r+2, t3=2r+3):
//   ph1:sA1(t1,b1) ph2:sB1(t1,b1) ph3:sA0(t2,b0) ph4:sB0(t2,b0)
//   ph5:sA1(t2,b0) ph6:sB1(t2,b0) ph7:sA0(t3,b1) ph8:sB0(t3,b1)
// Panel-death audit: b1-ks1 last read prev ph7-8 -> ph1-2 write OK;
// b0-ks0 last read ph1-2 -> ph3-4 write OK; b0-ks1 read ph3-4 -> ph5-6 OK;
// b1-ks0 read ph5-6 -> ph7-8 OK.
// vmcnt(6) at end of ph2/4/6/8 retires exactly the 3 loads needed 2 phases
// ahead (ledger: outstanding 9 -> 6; in flight never <6, never drained).
#define G2_PH(Q, KS, IH, STAGE_STMT, WVM) do {                                 \
    const __bf16* Ab_ = Afrag + (Q)*16384 + (KS)*8192 + (IH)*1024;             \
    bf16x8 af_[2];                                                             \
    _Pragma("unroll")                                                          \
    for (int i_ = 0; i_ < 2; ++i_) af_[i_] = *(const bf16x8*)(Ab_ + i_*512);   \
    if ((IH) == 0) {                                                           \
        const __bf16* Bb_ = Bfrag + (Q)*8192 + (KS)*4096;                      \
        _Pragma("unroll")                                                      \
        for (int j_ = 0; j_ < 4; ++j_) bfr[j_] = *(const bf16x8*)(Bb_ + j_*512);\
    }                                                                          \
    STAGE_STMT;                                                                \
    __builtin_amdgcn_s_barrier();                                              \
    __builtin_amdgcn_s_waitcnt(WAIT_LGKM0);                                    \
    __builtin_amdgcn_s_setprio(1);                                             \
    _Pragma("unroll")                                                          \
    for (int i_ = 0; i_ < 2; ++i_)                                             \
        _Pragma("unroll")                                                      \
        for (int j_ = 0; j_ < 4; ++j_)                                         \
            acc[(IH)*2+i_][j_] = __builtin_amdgcn_mfma_f32_16x16x32_bf16(      \
                af_[i_], bfr[j_], acc[(IH)*2+i_][j_], 0, 0, 0);                \
    __builtin_amdgcn_s_setprio(0);                                             \
    if ((WVM) >= 0) __builtin_amdgcn_s_waitcnt(WVM);                           \
    __builtin_amdgcn_s_barrier();                                              \
} while (0)

__global__ __launch_bounds__(512, 2) void gemm2_out(
    const __bf16* __restrict__ Ag, const __bf16* __restrict__ Bg,
    const float* __restrict__ Adiag, const float* __restrict__ h2,
    const float* __restrict__ z, float* __restrict__ out)
{
    constexpr int ldA = KEXT, ldB = KEXT;        // KITER = 65 tiles
    __shared__ __align__(16) __bf16 As[2 * 2 * 256 * 32];   // 64 KB
    __shared__ __align__(16) __bf16 Bs[2 * 2 * 128 * 32];   // 32 KB

    const int tid = threadIdx.x;
    const int wave = tid >> 6, lane = tid & 63;
    const int wm = wave >> 1, wn = wave & 1;     // 4M x 2N waves of 64x64
    const int row0 = blockIdx.x * 256;
    const int col0 = blockIdx.y * 128;

    const int csrc = ((tid & 3) ^ ((tid >> 3) & 3)) * 8;
    const __bf16* pA = Ag + (size_t)(row0 + (tid >> 2)) * ldA + csrc;  // rows 0..127
    const __bf16* pB = Bg + (size_t)(col0 + (tid >> 2)) * ldB + csrc;  // rows 0..127

    const int cswz = ((lane >> 4) ^ ((lane >> 1) & 3)) * 8;
    const __bf16* Afrag = As + (wm * 64 + (lane & 15)) * 32 + cswz;
    const __bf16* Bfrag = Bs + (wn * 64 + (lane & 15)) * 32 + cswz;

    // stage units (512 thr x 16B = 8KB/call)
    auto sA0 = [&](int t, int q) { const __bf16* a = pA + t * 64;
        __bf16* d = As + q * 16384 + wave * 512;
        async_copy16(a, d); async_copy16(a + (size_t)128 * ldA, d + 4096); };
    auto sA1 = [&](int t, int q) { const __bf16* a = pA + t * 64 + 32;
        __bf16* d = As + q * 16384 + 8192 + wave * 512;
        async_copy16(a, d); async_copy16(a + (size_t)128 * ldA, d + 4096); };
    auto sB0 = [&](int t, int q) { const __bf16* b = pB + t * 64;
        __bf16* d = Bs + q * 8192 + wave * 512;
        async_copy16(b, d); };
    auto sB1 = [&](int t, int q) { const __bf16* b = pB + t * 64 + 32;
        __bf16* d = Bs + q * 8192 + 4096 + wave * 512;
        async_copy16(b, d); };

    floatx4 acc[4][4];
#pragma unroll
    for (int i = 0; i < 4; ++i)
#pragma unroll
        for (int j = 0; j < 4; ++j) acc[i][j] = (floatx4)0.0f;
    bf16x8 bfr[4];

    // prologue: t0 full (buf0), t1 ks0 (buf1) = 9 loads; vm6 -> t0-ks0's
    // 3 loads retired (ph1-2's data).
    sA0(0, 0); sB0(0, 0); sA1(0, 0); sB1(0, 0);
    sA0(1, 1); sB0(1, 1);
    __builtin_amdgcn_s_waitcnt(WAIT_VM6);
    __builtin_amdgcn_s_barrier();

    for (int r = 0; r < 31; ++r) {               // tiles 0..61
        const int t1 = 2 * r + 1, t2 = 2 * r + 2, t3 = 2 * r + 3;
        G2_PH(0, 0, 0, sA1(t1, 1), -1);
        G2_PH(0, 0, 1, sB1(t1, 1), WAIT_VM6);
        G2_PH(0, 1, 0, sA0(t2, 0), -1);
        G2_PH(0, 1, 1, sB0(t2, 0), WAIT_VM6);
        G2_PH(1, 0, 0, sA1(t2, 0), -1);
        G2_PH(1, 0, 1, sB1(t2, 0), WAIT_VM6);
        G2_PH(1, 1, 0, sA0(t3, 1), -1);
        G2_PH(1, 1, 1, sB0(t3, 1), WAIT_VM6);
    }
    {   // tail: tiles 62 (buf0), 63 (buf1), 64 (buf0). Drains 6->6->6->3->0.
        G2_PH(0, 0, 0, sA1(63, 1), -1);
        G2_PH(0, 0, 1, sB1(63, 1), WAIT_VM6);
        G2_PH(0, 1, 0, sA0(64, 0), -1);
        G2_PH(0, 1, 1, sB0(64, 0), WAIT_VM6);
        G2_PH(1, 0, 0, sA1(64, 0), -1);
        G2_PH(1, 0, 1, sB1(64, 0), WAIT_VM6);
        G2_PH(1, 1, 0, (void)0,    -1);
        G2_PH(1, 1, 1, (void)0,    WAIT_VM3);
        G2_PH(0, 0, 0, (void)0,    -1);
        G2_PH(0, 0, 1, (void)0,    WAIT_VM0);
        G2_PH(0, 1, 0, (void)0,    -1);
        G2_PH(0, 1, 1, (void)0,    -1);
    }

    const int r0 = row0 + wm * 64 + (lane >> 4) * 4;
    const int c0 = col0 + wn * 64 + (lane & 15);
#pragma unroll
    for (int i = 0; i < 4; ++i) {
#pragma unroll
        for (int j = 0; j < 4; ++j) {
            const int c = c0 + j * 16;
            const float aj = Adiag[c];
            const float hj = h2[c];
#pragma unroll
            for (int rg = 0; rg < 4; ++rg) {
                const int r = r0 + i * 16 + rg;
                out[(size_t)r * DZ + c] =
                    acc[i][j][rg] + aj * z[(size_t)r * DZ + c] + hj;
            }
        }
    }
}

// ---------------- launch ----------------

extern "C" void kernel_launch(void* const* d_in, const int* in_sizes, int n_in,
                              void* d_out, int out_size, void* d_ws, size_t ws_size,
                              hipStream_t stream) {
    const float* z  = (const float*)d_in[0];   // [8192,1024]
    const float* s  = (const float*)d_in[1];   // [8192,64]
    const float* A  = (const float*)d_in[2];   // [1024]
    const float* W1 = (const float*)d_in[3];   // [4096,1024]
    const float* W2 = (const float*)d_in[4];   // [1024,4096]
    const float* h1 = (const float*)d_in[5];   // [4096]
    const float* h2 = (const float*)d_in[6];   // [1024]
    const float* C  = (const float*)d_in[7];   // [1024,64]
    float* out = (float*)d_out;

    // workspace layout (bytes): Hb | zb | W1b | B2b  ~= 102 MB total
    char* ws = (char*)d_ws;
    size_t offHb  = 0;
    size_t offZb  = offHb  + (size_t)BB * KEXT * 2;
    size_t offW1b = offZb  + (size_t)BB * DZ * 2;
    size_t offB2b = offW1b + (size_t)DH * DZ * 2;
    __bf16* Hb  = (__bf16*)(ws + offHb);    // [8192 x 4160]
    __bf16* zb  = (__bf16*)(ws + offZb);    // [8192 x 1024]
    __bf16* W1b = (__bf16*)(ws + offW1b);   // [4096 x 1024]
    __bf16* B2b = (__bf16*)(ws + offB2b);   // [1024 x 4160] = [W2 | C]

    prep_all<<<2048, 256, 0, stream>>>(z, W1, W2, C, s, zb, W1b, B2b, Hb);
    gemm1_relu<<<dim3(BB / 256, DH / 128), 512, 0, stream>>>(zb, W1b, h1, Hb);
    gemm2_out<<<dim3(BB / 256, DZ / 128), 512, 0, stream>>>(Hb, B2b, A, h2, z, out);
}

// Round 12
// 254.854 us; speedup vs baseline: 1.1040x; 1.1040x over previous
//
#include <hip/hip_runtime.h>

// Problem constants (fixed shapes)
#define BB 8192      // batch
#define DZ 1024
#define DS 64
#define DH 4096
#define KEXT (DH + DS)   // 4160: K of GEMM2 = [H | s]

typedef float floatx4 __attribute__((ext_vector_type(4)));
typedef __bf16 bf16x8 __attribute__((ext_vector_type(8)));
typedef __attribute__((address_space(1))) void* as1_void_ptr;
typedef __attribute__((address_space(3))) void* as3_void_ptr;

// s_waitcnt immediates (gfx9: vmcnt[3:0] bits0-3 + [5:4] bits15:14,
// expcnt bits6:4, lgkmcnt bits11:8). lgkm=15,exp=7 "unconstrained" base = 3952.
#define WAIT_VM0   3952   // vmcnt(0)
#define WAIT_VM8   3960   // vmcnt(8)
#define WAIT_LGKM0 49279  // lgkmcnt(0), vm/exp unconstrained

__device__ __forceinline__ void async_copy16(const void* g, void* l) {
    // global -> LDS direct copy, 16B/lane; per-lane GLOBAL address,
    // wave-uniform LDS base + lane*16 dest.
    __builtin_amdgcn_global_load_lds((as1_void_ptr)g, (as3_void_ptr)l, 16, 0, 0);
}

__device__ __forceinline__ bf16x8 cvt8(float4 a, float4 b) {
    bf16x8 o = { (__bf16)a.x, (__bf16)a.y, (__bf16)a.z, (__bf16)a.w,
                 (__bf16)b.x, (__bf16)b.y, (__bf16)b.z, (__bf16)b.w };
    return o;
}

// LDS bank-conflict swizzle (VERIFIED R1: SQ_LDS_BANK_CONFLICT 8.5M -> 0):
// Panels are [rows x 32] bf16 row-major => 64B row stride. Physical 16B
// chunk p of row r holds K-chunk p ^ ((r>>1)&3). gload_lds staging:
// thread t (row t>>2, phys chunk t&3) loads global chunk (t&3)^((t>>3)&3).
// Read side: chunk = (lane>>4) ^ ((lane>>1)&3).
//
// FINAL SESSION LEDGER (all counter-verified):
//   R1: swizzle -> conflicts 8.5M->0. Real gain on gemm1 (3 blk/CU, LDS on
//       critical path); timing-null on lockstep gemm2 (regime gate, m252).
//   R1: gemm1 256x256 2-phase (1 blk/CU): REGRESSED 75->93.
//   R3: gemm2 BK=32 + setprio: REGRESSED 91->97.5 (setprio starves
//       staging waves in barrier-synced GEMM; kt-overhead doubled).
//   R6: f32-A reg-staging: REGRESSED 75->182 (latency chain + refetch).
//   R8: gemm1 8-phase (128KB, 1 blk/CU): REGRESSED ~75->~84+.
//   R11: gemm2 8-phase (96KB, 1 blk/CU): REGRESSED 85->99, MfmaUtil
//       33->28 (16 barriers + 8 lgkm-drains per 2 tiles > interleave
//       gain at 2 waves/SIMD; no third wave to cover ds_read latency).
//   R1/R4/R6 prep sweep: prep is BW-bound (~15us @100MB); ~75us/iter is
//       fixed harness overhead (reset dispatches) -- not addressable.
//   CONVERGED: gemm1 74.6us = 921 TF (m97-structure ceiling, 3 blk/CU
//       cross-block overlap); gemm2 85-88us ~= 810 TF (invariant across
//       FOUR schedules). HBM 11-17%, conflicts 0. Three hand-pipelined
//       restructures (R3/R8/R11) all lost to counted-vmcnt 2-phase +
//       max residency: on these short-K shapes, block-level TLP is the
//       pipeline, and my static interleaves cost more in sync than they
//       recover (HK-quality ordering not reproduced; m232-analog null).
// R12 = final revert to best-known composite (R7/R10 config: 250.8/261.4).

// ---------------- prep: streaming f32->bf16 repack ----------------
__global__ __launch_bounds__(256) void prep_all(
    const float* __restrict__ z, const float* __restrict__ W1,
    const float* __restrict__ W2, const float* __restrict__ C,
    const float* __restrict__ s,
    __bf16* __restrict__ zb, __bf16* __restrict__ W1b,
    __bf16* __restrict__ B2b, __bf16* __restrict__ Hb)
{
    constexpr int NC_Z  = (BB * DZ) / 8;          // 1048576
    constexpr int NC_W1 = (DH * DZ) / 8;          // 524288
    constexpr int NC_B2 = (DZ * KEXT) / 8;        // 532480 (1024 rows x 520)
    constexpr int NC_S  = (BB * DS) / 8;          // 65536
    constexpr int NC_TOT = NC_Z + NC_W1 + NC_B2 + NC_S;
    const int stride = gridDim.x * blockDim.x;
    for (int c = blockIdx.x * blockDim.x + threadIdx.x; c < NC_TOT; c += stride) {
        const float4* src;
        __bf16* dst;
        if (c < NC_Z) {
            src = (const float4*)z + (size_t)c * 2;
            dst = zb + (size_t)c * 8;
        } else if (c < NC_Z + NC_W1) {
            int i = c - NC_Z;
            src = (const float4*)W1 + (size_t)i * 2;
            dst = W1b + (size_t)i * 8;
        } else if (c < NC_Z + NC_W1 + NC_B2) {
            int i = c - (NC_Z + NC_W1);
            int j = i / 520, p = i - j * 520;     // row j of B2b, chunk p
            int h = p * 8;
            const float* sp = (h < DH) ? (W2 + (size_t)j * DH + h)
                                       : (C  + (size_t)j * DS + (h - DH));
            src = (const float4*)sp;
            dst = B2b + (size_t)j * KEXT + h;
        } else {
            int i = c - (NC_Z + NC_W1 + NC_B2);
            int r = i >> 3, k = (i & 7) * 8;      // row r of s, 8-elem chunk
            src = (const float4*)(s + (size_t)r * DS + k);
            dst = Hb + (size_t)r * KEXT + DH + k;
        }
        float4 a = src[0], b = src[1];
        *(bf16x8*)dst = cvt8(a, b);
    }
}

// ---------------- GEMM1: Hb[:, :4096] = relu(zb @ W1b^T + h1) ----------------
// R4-PROVEN FORM (best known: ~74.6us = 921 TF). A = zb bf16 via gload_lds,
// 256x128 tile, 8 waves of 64x64, BK=64, single-buffer full-drain, 48 KB
// LDS, 88 VGPR -> 3 blocks/CU. Cross-block overlap is the pipeline.
__global__ __launch_bounds__(512, 4) void gemm1_relu(
    const __bf16* __restrict__ Ag, const __bf16* __restrict__ Bg,
    const float* __restrict__ h1, __bf16* __restrict__ Hb)
{
    constexpr int ldA = DZ, ldB = DZ, KITER = DZ / 64;
    __shared__ __align__(16) __bf16 As[256 * 64];   // 32 KB (2 panels of 256x32)
    __shared__ __align__(16) __bf16 Bs[128 * 64];   // 16 KB (2 panels of 128x32)

    const int tid = threadIdx.x;
    const int wave = tid >> 6, lane = tid & 63;
    const int wm = wave >> 1, wn = wave & 1;
    const int row0 = blockIdx.x * 256;
    const int col0 = blockIdx.y * 128;

    const int csrc = ((tid & 3) ^ ((tid >> 3) & 3)) * 8;   // swizzled src chunk
    const __bf16* pA = Ag + (size_t)(row0 + (tid >> 2)) * ldA + csrc;
    const __bf16* pB = Bg + (size_t)(col0 + ((tid >> 2) & 127)) * ldB + csrc;
    __bf16* lA = As + wave * 512;   // + lane*16B implicit (8 waves cover 128 rows)
    __bf16* lB = Bs + wave * 512;

    const int cswz = ((lane >> 4) ^ ((lane >> 1) & 3)) * 8; // swizzled read chunk
    const __bf16* Afrag = As + (wm * 64 + (lane & 15)) * 32 + cswz;
    const __bf16* Bfrag = Bs + (wn * 64 + (lane & 15)) * 32 + cswz;

    floatx4 acc[4][4];
#pragma unroll
    for (int i = 0; i < 4; ++i)
#pragma unroll
        for (int j = 0; j < 4; ++j) acc[i][j] = (floatx4)0.0f;

    for (int kt = 0; kt < KITER; ++kt) {
        const __bf16* ak = pA + kt * 64;
        const __bf16* bk = pB + kt * 64;
        // A: rows 0-127 / 128-255, panels k+0 / k+32
        async_copy16(ak,                           lA);
        async_copy16(ak + (size_t)128 * ldA,       lA + 4096);
        async_copy16(ak + 32,                      lA + 8192);
        async_copy16(ak + (size_t)128 * ldA + 32,  lA + 8192 + 4096);
        // B: 128 rows, panels k+0 / k+32
        async_copy16(bk,                           lB);
        async_copy16(bk + 32,                      lB + 4096);
        __builtin_amdgcn_s_waitcnt(0);
        __syncthreads();

#pragma unroll
        for (int ks = 0; ks < 2; ++ks) {
            bf16x8 af[4], bfr[4];
#pragma unroll
            for (int i = 0; i < 4; ++i) af[i] = *(const bf16x8*)(Afrag + ks * 8192 + i * 16 * 32);
#pragma unroll
            for (int j = 0; j < 4; ++j) bfr[j] = *(const bf16x8*)(Bfrag + ks * 4096 + j * 16 * 32);
#pragma unroll
            for (int i = 0; i < 4; ++i)
#pragma unroll
                for (int j = 0; j < 4; ++j)
                    acc[i][j] = __builtin_amdgcn_mfma_f32_16x16x32_bf16(af[i], bfr[j], acc[i][j], 0, 0, 0);
        }
        __syncthreads();
    }

    // epilogue: C/D layout col = lane&15, row = (lane>>4)*4 + reg
    const int r0 = row0 + wm * 64 + (lane >> 4) * 4;
    const int c0 = col0 + wn * 64 + (lane & 15);
#pragma unroll
    for (int i = 0; i < 4; ++i) {
#pragma unroll
        for (int j = 0; j < 4; ++j) {
            int c = c0 + j * 16;
            float bias = h1[c];
#pragma unroll
            for (int rg = 0; rg < 4; ++rg) {
                int r = r0 + i * 16 + rg;
                float v = acc[i][j][rg] + bias;
                v = v > 0.0f ? v : 0.0f;
                Hb[(size_t)r * KEXT + c] = (__bf16)v;
            }
        }
    }
}

// ---------------- GEMM2: out = Hb @ B2b^T + A*z + h2 ----------------
// R7-PROVEN FORM (best known: ~85-88us): 128x128 tile, 4 waves of 64x64,
// BK=64, dbuf 64 KB, 512 blocks (2/CU), counted vmcnt(8), f32-z epilogue.
__global__ __launch_bounds__(256, 2) void gemm2_out(
    const __bf16* __restrict__ Ag, const __bf16* __restrict__ Bg,
    const float* __restrict__ Adiag, const float* __restrict__ h2,
    const float* __restrict__ z, float* __restrict__ out)
{
    constexpr int ldA = KEXT, ldB = KEXT, KITER = KEXT / 64;   // 65
    __shared__ __align__(16) __bf16 As[2 * 128 * 64];   // 32 KB dbuf
    __shared__ __align__(16) __bf16 Bs[2 * 128 * 64];   // 32 KB dbuf

    const int tid = threadIdx.x;
    const int wave = tid >> 6, lane = tid & 63;
    const int wm = wave >> 1, wn = wave & 1;            // 2x2 waves of 64x64
    const int row0 = blockIdx.x * 128;
    const int col0 = blockIdx.y * 128;

    const int csrc = ((tid & 3) ^ ((tid >> 3) & 3)) * 8;   // swizzled src chunk
    const __bf16* pA = Ag + (size_t)(row0 + (tid >> 2)) * ldA + csrc;   // rows 0..63
    const __bf16* pB = Bg + (size_t)(col0 + (tid >> 2)) * ldB + csrc;

    const int cswz = ((lane >> 4) ^ ((lane >> 1) & 3)) * 8; // swizzled read chunk
    const __bf16* Afrag = As + (wm * 64 + (lane & 15)) * 32 + cswz;
    const __bf16* Bfrag = Bs + (wn * 64 + (lane & 15)) * 32 + cswz;

    floatx4 acc[4][4];
#pragma unroll
    for (int i = 0; i < 4; ++i)
#pragma unroll
        for (int j = 0; j < 4; ++j) acc[i][j] = (floatx4)0.0f;

    auto issue = [&](int kt, int q) {
        const __bf16* ak = pA + kt * 64;
        const __bf16* bk = pB + kt * 64;
        __bf16* lA = As + q * 8192 + wave * 512;
        __bf16* lB = Bs + q * 8192 + wave * 512;
        async_copy16(ak,                          lA);
        async_copy16(ak + (size_t)64 * ldA,       lA + 2048);
        async_copy16(ak + 32,                     lA + 4096);
        async_copy16(ak + (size_t)64 * ldA + 32,  lA + 4096 + 2048);
        async_copy16(bk,                          lB);
        async_copy16(bk + (size_t)64 * ldB,       lB + 2048);
        async_copy16(bk + 32,                     lB + 4096);
        async_copy16(bk + (size_t)64 * ldB + 32,  lB + 4096 + 2048);
    };

    issue(0, 0);   // prologue

    for (int kt = 0; kt < KITER; ++kt) {
        const int p = kt & 1;
        if (kt + 1 < KITER) {
            issue(kt + 1, p ^ 1);
            __builtin_amdgcn_s_waitcnt(WAIT_VM8);   // tile kt's 8 done; 8 in flight
        } else {
            __builtin_amdgcn_s_waitcnt(WAIT_VM0);
        }
        __builtin_amdgcn_s_barrier();

#pragma unroll
        for (int ks = 0; ks < 2; ++ks) {
            const __bf16* Ab = Afrag + p * 8192 + ks * 4096;
            const __bf16* Bb = Bfrag + p * 8192 + ks * 4096;
            bf16x8 af[4], bfr[4];
#pragma unroll
            for (int i = 0; i < 4; ++i) af[i] = *(const bf16x8*)(Ab + i * 16 * 32);
#pragma unroll
            for (int j = 0; j < 4; ++j) bfr[j] = *(const bf16x8*)(Bb + j * 16 * 32);
#pragma unroll
            for (int i = 0; i < 4; ++i)
#pragma unroll
                for (int j = 0; j < 4; ++j)
                    acc[i][j] = __builtin_amdgcn_mfma_f32_16x16x32_bf16(af[i], bfr[j], acc[i][j], 0, 0, 0);
        }

        __builtin_amdgcn_s_waitcnt(WAIT_LGKM0);     // reads of buf p done
        __builtin_amdgcn_s_barrier();               // safe to refill buf p
    }

    const int r0 = row0 + wm * 64 + (lane >> 4) * 4;
    const int c0 = col0 + wn * 64 + (lane & 15);
#pragma unroll
    for (int i = 0; i < 4; ++i) {
#pragma unroll
        for (int j = 0; j < 4; ++j) {
            const int c = c0 + j * 16;
            const float aj = Adiag[c];
            const float hj = h2[c];
#pragma unroll
            for (int rg = 0; rg < 4; ++rg) {
                const int r = r0 + i * 16 + rg;
                out[(size_t)r * DZ + c] =
                    acc[i][j][rg] + aj * z[(size_t)r * DZ + c] + hj;
            }
        }
    }
}

// ---------------- launch ----------------

extern "C" void kernel_launch(void* const* d_in, const int* in_sizes, int n_in,
                              void* d_out, int out_size, void* d_ws, size_t ws_size,
                              hipStream_t stream) {
    const float* z  = (const float*)d_in[0];   // [8192,1024]
    const float* s  = (const float*)d_in[1];   // [8192,64]
    const float* A  = (const float*)d_in[2];   // [1024]
    const float* W1 = (const float*)d_in[3];   // [4096,1024]
    const float* W2 = (const float*)d_in[4];   // [1024,4096]
    const float* h1 = (const float*)d_in[5];   // [4096]
    const float* h2 = (const float*)d_in[6];   // [1024]
    const float* C  = (const float*)d_in[7];   // [1024,64]
    float* out = (float*)d_out;

    // workspace layout (bytes): Hb | zb | W1b | B2b  ~= 102 MB total
    char* ws = (char*)d_ws;
    size_t offHb  = 0;
    size_t offZb  = offHb  + (size_t)BB * KEXT * 2;
    size_t offW1b = offZb  + (size_t)BB * DZ * 2;
    size_t offB2b = offW1b + (size_t)DH * DZ * 2;
    __bf16* Hb  = (__bf16*)(ws + offHb);    // [8192 x 4160]
    __bf16* zb  = (__bf16*)(ws + offZb);    // [8192 x 1024]
    __bf16* W1b = (__bf16*)(ws + offW1b);   // [4096 x 1024]
    __bf16* B2b = (__bf16*)(ws + offB2b);   // [1024 x 4160] = [W2 | C]

    prep_all<<<2048, 256, 0, stream>>>(z, W1, W2, C, s, zb, W1b, B2b, Hb);
    gemm1_relu<<<dim3(BB / 256, DH / 128), 512, 0, stream>>>(zb, W1b, h1, Hb);
    gemm2_out<<<dim3(BB / 128, DZ / 128), 256, 0, stream>>>(Hb, B2b, A, h2, z, out);
}